// Round 11
// baseline (265.270 us; speedup 1.0000x reference)
//
#include <hip/hip_runtime.h>
#include <math.h>

#define N_NODES 50000
#define N_EDGES 800000
#define DEG_CAP 64   // max in-degree ~45 (Poisson mean 16); cap for LDS meta arrays

// two-pass binning CSR builder (no per-edge global atomics, coalesced stores):
// pass1 (prep strip): 250 blocks x 3200 edges -> 98 buckets of 512 nodes
// pass2 (gemm1 strip): 98 blocks, LDS counting sort -> dense CSR + packed meta
#define NB 98
#define BCAP 10240   // mean 8192, std ~90 -> 22 sigma headroom
#define BIN_BLKS 250
#define CONV_BLKS 256

typedef __attribute__((ext_vector_type(8))) short bf16x8;
typedef __attribute__((ext_vector_type(4))) float f32x4;
typedef __attribute__((ext_vector_type(2))) float f32x2;

__device__ __forceinline__ float leaky(float x) { return x >= 0.f ? x : 0.2f * x; }
__device__ __forceinline__ unsigned short f2bf(float f) {
  unsigned u = __float_as_uint(f);
  return (unsigned short)((u + 0x7fffu + ((u >> 16) & 1u)) >> 16);
}
__device__ __forceinline__ float bflo(unsigned u) { return __uint_as_float(u << 16); }
__device__ __forceinline__ float bfhi(unsigned u) { return __uint_as_float(u & 0xffff0000u); }
__device__ __forceinline__ unsigned pack2(float a, float b) {
  return (unsigned)f2bf(a) | ((unsigned)f2bf(b) << 16);
}
__device__ __forceinline__ unsigned pack2u(unsigned a, unsigned b) {
  return pack2(__uint_as_float(a), __uint_as_float(b));
}

// ---------- prep: binning pass1 strip (FIRST) + weight packs ----------
__launch_bounds__(256)
__global__ void prep_k(const float* __restrict__ W1, const float* __restrict__ W2,
                       const float* __restrict__ resW2, short* __restrict__ Wt1,
                       short* __restrict__ Wt2, const int* __restrict__ src,
                       const int* __restrict__ dst, unsigned* __restrict__ gcnt,
                       unsigned* __restrict__ bbuf) {
  __shared__ int hist[NB];
  __shared__ int basev[NB];
  if (blockIdx.x < BIN_BLKS) {
    const int e0 = blockIdx.x * (N_EDGES / BIN_BLKS);  // 3200 edges per block
    for (int i = threadIdx.x; i < NB; i += 256) hist[i] = 0;
    __syncthreads();
    for (int i = threadIdx.x; i < N_EDGES / BIN_BLKS; i += 256)
      atomicAdd(&hist[dst[e0 + i] >> 9], 1);
    __syncthreads();
    for (int b = threadIdx.x; b < NB; b += 256)
      basev[b] = (int)atomicAdd(&gcnt[b], (unsigned)hist[b]);  // 98 atomics/block
    __syncthreads();
    for (int i = threadIdx.x; i < NB; i += 256) hist[i] = 0;
    __syncthreads();
    for (int i = threadIdx.x; i < N_EDGES / BIN_BLKS; i += 256) {
      int d = dst[e0 + i], s = src[e0 + i];  // L2-hot re-read
      int b = d >> 9;
      int ofs = atomicAdd(&hist[b], 1);
      bbuf[(size_t)b * BCAP + basev[b] + ofs] =
          (unsigned)s | ((unsigned)(d & 511) << 16);
    }
    return;
  }
  const int gtid = (blockIdx.x - BIN_BLKS) * 256 + threadIdx.x;
  const int gsz = CONV_BLKS * 256;
  for (int idx = gtid; idx < 256 * 256; idx += gsz) {
    int n = idx >> 8, k = idx & 255;
    Wt1[idx] = (short)f2bf(W1[(size_t)k * 256 + n]);
  }
  for (int idx = gtid; idx < 128 * 256; idx += gsz) {
    int n = idx >> 8, k = idx & 255;
    float v = (n < 64) ? W2[(size_t)k * 64 + n] : resW2[(size_t)k * 64 + (n - 64)];
    Wt2[idx] = (short)f2bf(v);
  }
}

// ---------- bf16 MFMA GEMM with fused el/er row-dot + LDS-coalesced C store ----------
// MODE 0: A is FP32 (feat), converted to bf16 in-register during staging.
//         SCAT: blockIdx.y==0 (dispatched FIRST) runs binning pass2 (x<NB):
//         LDS counting sort -> dense CSR (coalesced 2B stores) + meta pack.
//         GEMM tiles at y in {1,2} with bn0=(y-1)*128.
// MODE 1: A is bf16 (h1b). N=128; cols<64 -> bf16 Cb + el/er; cols>=64 -> fp32 Cf.
template <int MODE, bool SCAT>
__launch_bounds__(256)
__global__ void mfma_gemm_k(const short* __restrict__ A, const float* __restrict__ Af,
                            const short* __restrict__ Bt,
                            const float* __restrict__ bias, const float* __restrict__ al,
                            const float* __restrict__ ar, float* __restrict__ elp,
                            float* __restrict__ erp, short* __restrict__ Cb,
                            float* __restrict__ Cf, const unsigned* __restrict__ gcnt,
                            const unsigned* __restrict__ bbuf,
                            unsigned* __restrict__ meta,
                            unsigned short* __restrict__ csr, int M, int K, int N) {
  constexpr int EPI_COLS = (MODE == 0) ? 136 : 72;  // padded bf16 row stride
  union SharedU {
    struct { short As[4][128][8]; short Bs[4][128][8]; } ab;
    short epi[128 * EPI_COLS];
    struct { int h[512]; int o[512]; unsigned short s[BCAP]; } p2;  // 24.5 KB
  };
  __shared__ SharedU sh;
  __shared__ int wsum[4];

  if (SCAT && blockIdx.y == 0) {
    // binning pass2: counting sort per bucket -> CSR + meta (all stores coalesced)
    if (blockIdx.x >= NB) return;
    const int b = blockIdx.x;
    const int tid = threadIdx.x;
    int* h = sh.p2.h;
    int* o = sh.p2.o;
    unsigned short* srt = sh.p2.s;
    for (int i = tid; i < 512; i += 256) h[i] = 0;
    __syncthreads();
    const int nb = min((int)gcnt[b], BCAP);
    const unsigned* bp = bbuf + (size_t)b * BCAP;
    for (int i = tid; i < nb; i += 256) atomicAdd(&h[bp[i] >> 16], 1);
    __syncthreads();
    // exclusive prefix over 512 counters: 2 elems/thread + wave shfl-scan
    const int lane = tid & 63, wvi = tid >> 6;
    int h0 = h[tid * 2], h1 = h[tid * 2 + 1];
    int s2 = h0 + h1;
    int v = s2;
#pragma unroll
    for (int d = 1; d < 64; d <<= 1) {
      int t = __shfl_up(v, d);
      if (lane >= d) v += t;
    }
    if (lane == 63) wsum[wvi] = v;
    __syncthreads();
    int wexcl = 0;
    for (int j = 0; j < wvi; ++j) wexcl += wsum[j];
    int excl = wexcl + v - s2;  // exclusive prefix for element 2*tid
    o[tid * 2] = excl;
    o[tid * 2 + 1] = excl + h0;
    __syncthreads();
    // bucket base in csr (prefix over buckets; 98 L2-hot reads)
    int bbase = 0;
    for (int j = 0; j < b; ++j) bbase += min((int)gcnt[j], BCAP);
    // meta pack (before scatter mutates o)
    for (int i = tid; i < 512; i += 256) {
      int node = (b << 9) + i;
      if (node < N_NODES)
        meta[node] = (unsigned)(bbase + o[i]) | ((unsigned)min(h[i], DEG_CAP) << 25);
    }
    __syncthreads();
    // scatter into sorted LDS
    for (int i = tid; i < nb; i += 256) {
      unsigned e = bp[i];
      int pos = atomicAdd(&o[e >> 16], 1);
      srt[pos] = (unsigned short)(e & 0xFFFFu);
    }
    __syncthreads();
    // coalesced dense write-out
    for (int i = tid; i < nb; i += 256) csr[bbase + i] = srt[i];
    return;
  }
  const int tid = threadIdx.x;
  const int bm0 = blockIdx.x * 128;
  const int bn0 = (SCAT ? ((int)blockIdx.y - 1) : (int)blockIdx.y) * 128;
  const int wave = tid >> 6, lane = tid & 63;
  const int wm = (wave & 1) * 64, wn = (wave >> 1) * 64;
  const int q = lane >> 4, r16 = lane & 15;
  const int srow = tid >> 1, sk = (tid & 1) * 16, sq = (tid & 1) * 2;
  f32x4 acc[4][4] = {};

  for (int k0 = 0; k0 < K; k0 += 32) {
    if (MODE == 0) {
      // FP32 A: load 16 floats (4x uint4), pack to bf16 in-register
      uint4 w0 = {0, 0, 0, 0}, w1 = {0, 0, 0, 0}, w2 = {0, 0, 0, 0}, w3 = {0, 0, 0, 0};
      if (bm0 + srow < M) {
        const uint4* p = (const uint4*)(Af + (size_t)(bm0 + srow) * K + k0 + sk);
        w0 = p[0];
        w1 = p[1];
        w2 = p[2];
        w3 = p[3];
      }
      uint4 v0, v1;
      v0.x = pack2u(w0.x, w0.y);
      v0.y = pack2u(w0.z, w0.w);
      v0.z = pack2u(w1.x, w1.y);
      v0.w = pack2u(w1.z, w1.w);
      v1.x = pack2u(w2.x, w2.y);
      v1.y = pack2u(w2.z, w2.w);
      v1.z = pack2u(w3.x, w3.y);
      v1.w = pack2u(w3.z, w3.w);
      *(uint4*)&sh.ab.As[sq][srow][0] = v0;
      *(uint4*)&sh.ab.As[sq + 1][srow][0] = v1;
    } else {
      uint4 v0 = {0, 0, 0, 0}, v1 = {0, 0, 0, 0};
      if (bm0 + srow < M) {
        const uint4* p = (const uint4*)(A + (size_t)(bm0 + srow) * K + k0 + sk);
        v0 = p[0];
        v1 = p[1];
      }
      *(uint4*)&sh.ab.As[sq][srow][0] = v0;
      *(uint4*)&sh.ab.As[sq + 1][srow][0] = v1;
    }
    {
      const uint4* p = (const uint4*)(Bt + (size_t)(bn0 + srow) * K + k0 + sk);
      *(uint4*)&sh.ab.Bs[sq][srow][0] = p[0];
      *(uint4*)&sh.ab.Bs[sq + 1][srow][0] = p[1];
    }
    __syncthreads();
    bf16x8 af[4], bfr[4];
#pragma unroll
    for (int i = 0; i < 4; ++i) af[i] = *(const bf16x8*)&sh.ab.As[q][wm + i * 16 + r16][0];
#pragma unroll
    for (int j = 0; j < 4; ++j) bfr[j] = *(const bf16x8*)&sh.ab.Bs[q][wn + j * 16 + r16][0];
#pragma unroll
    for (int i = 0; i < 4; ++i)
#pragma unroll
      for (int j = 0; j < 4; ++j)
        acc[i][j] = __builtin_amdgcn_mfma_f32_16x16x32_bf16(af[i], bfr[j], acc[i][j], 0, 0, 0);
    __syncthreads();
  }

  // fused el/er row-dot: this wave's 64 cols are exactly one head (regs only)
  if (MODE == 0 || wn == 0) {
    const int head = (bn0 + wn) >> 6;
    float alv[4], arv[4];
#pragma unroll
    for (int j = 0; j < 4; ++j) {
      alv[j] = al[((MODE == 0) ? head * 64 : 0) + j * 16 + r16];
      arv[j] = ar[((MODE == 0) ? head * 64 : 0) + j * 16 + r16];
    }
#pragma unroll
    for (int i = 0; i < 4; ++i) {
#pragma unroll
      for (int reg = 0; reg < 4; ++reg) {
        float dl = acc[i][0][reg] * alv[0] + acc[i][1][reg] * alv[1] +
                   acc[i][2][reg] * alv[2] + acc[i][3][reg] * alv[3];
        float dr = acc[i][0][reg] * arv[0] + acc[i][1][reg] * arv[1] +
                   acc[i][2][reg] * arv[2] + acc[i][3][reg] * arv[3];
#pragma unroll
        for (int mm = 1; mm < 16; mm <<= 1) {
          dl += __shfl_xor(dl, mm);
          dr += __shfl_xor(dr, mm);
        }
        int row_g = bm0 + wm + i * 16 + q * 4 + reg;
        if (r16 == 0 && row_g < M) {
          if (MODE == 0) {
            elp[(size_t)row_g * 4 + head] = dl;
            erp[(size_t)row_g * 4 + head] = dr;
          } else {
            elp[row_g] = dl;
            erp[row_g] = dr;
          }
        }
      }
    }
  }

  // ---- C store via LDS transpose -> coalesced uint4 ----
  if (MODE == 0) {
#pragma unroll
    for (int i = 0; i < 4; ++i)
#pragma unroll
      for (int reg = 0; reg < 4; ++reg) {
        int row = wm + i * 16 + q * 4 + reg;
#pragma unroll
        for (int j = 0; j < 4; ++j)
          sh.epi[row * EPI_COLS + wn + j * 16 + r16] = (short)f2bf(acc[i][j][reg]);
      }
    __syncthreads();
#pragma unroll
    for (int k = 0; k < 8; ++k) {
      int c = k * 256 + tid;          // 2048 chunks of 16B
      int row = c >> 4, cc = c & 15;  // 128 rows x 16 chunks
      int row_g = bm0 + row;
      if (row_g < M) {
        uint4 v = *(const uint4*)&sh.epi[row * EPI_COLS + cc * 8];
        *(uint4*)(Cb + (size_t)row_g * N + bn0 + cc * 8) = v;
      }
    }
  } else {
    if (wn == 0) {
#pragma unroll
      for (int i = 0; i < 4; ++i)
#pragma unroll
        for (int reg = 0; reg < 4; ++reg) {
          int row = wm + i * 16 + q * 4 + reg;
#pragma unroll
          for (int j = 0; j < 4; ++j)
            sh.epi[row * EPI_COLS + j * 16 + r16] = (short)f2bf(acc[i][j][reg]);
        }
    } else {
#pragma unroll
      for (int i = 0; i < 4; ++i)
#pragma unroll
        for (int reg = 0; reg < 4; ++reg) {
          int row_g = bm0 + wm + i * 16 + q * 4 + reg;
          if (row_g >= M) continue;
#pragma unroll
          for (int j = 0; j < 4; ++j) {
            int col = j * 16 + r16;
            Cf[(size_t)row_g * 64 + col] = acc[i][j][reg] + bias[col];
          }
        }
    }
    __syncthreads();
#pragma unroll
    for (int k = 0; k < 4; ++k) {
      int c = k * 256 + tid;         // 1024 chunks of 16B
      int row = c >> 3, cc = c & 7;  // 128 rows x 8 chunks
      int row_g = bm0 + row;
      if (row_g < M) {
        uint4 v = *(const uint4*)&sh.epi[row * EPI_COLS + cc * 8];
        *(uint4*)(Cb + (size_t)row_g * 64 + cc * 8) = v;
      }
    }
  }
}

// ---------- layer-1 aggregate: 2 independent nodes per wave (cross-node ILP) ----------
// CSR-based: meta[node] = start | (deg<<25). node0 splits into two half dispatches
// (visibility round: lets prep/gemm1/agg2 surface in the top-5).
#define AGG1_FMA(ACC, U, W)                     \
  {                                             \
    f32x2 w2_ = {(W), (W)};                     \
    ACC[0] += w2_ * (f32x2){bflo((U).x), bfhi((U).x)}; \
    ACC[1] += w2_ * (f32x2){bflo((U).y), bfhi((U).y)}; \
    ACC[2] += w2_ * (f32x2){bflo((U).z), bfhi((U).z)}; \
    ACC[3] += w2_ * (f32x2){bflo((U).w), bfhi((U).w)}; \
  }

__launch_bounds__(256)
__global__ void agg1_k(const unsigned short* __restrict__ csr,
                       const unsigned* __restrict__ meta,
                       const float* __restrict__ el, const float* __restrict__ er,
                       const short* __restrict__ ft, const float* __restrict__ bias,
                       short* __restrict__ h1, int node0) {
  __shared__ uint2 wmeta[4][2][64][4];  // [wave][node][slot][head] = {byte-ofs, w/denom}
  const int wv = threadIdx.x >> 6;
  const int lane = threadIdx.x & 63;
  const int nodeA = node0 + blockIdx.x * 8 + wv * 2;
  const int nodeB = nodeA + 1;
  const unsigned mA = meta[nodeA], mB = meta[nodeB];
  const int degA = (int)(mA >> 25), degB = (int)(mB >> 25);
  const unsigned short* rowA = csr + (mA & 0x1FFFFFFu);
  const unsigned short* rowB = csr + (mB & 0x1FFFFFFu);

  {  // interleaved prologue (same wave produces & consumes: no barrier)
    int sA = lane < degA ? (int)rowA[lane] : (degA > 0 ? (int)rowA[0] : 0);
    int sB = lane < degB ? (int)rowB[lane] : (degB > 0 ? (int)rowB[0] : 0);
    float4 elA = *(const float4*)(el + (size_t)sA * 4);
    float4 elB = *(const float4*)(el + (size_t)sB * 4);
    float4 erA = *(const float4*)(er + (size_t)nodeA * 4);
    float4 erB = *(const float4*)(er + (size_t)nodeB * 4);
    float a0 = lane < degA ? __expf(leaky(elA.x + erA.x)) : 0.f;
    float a1 = lane < degA ? __expf(leaky(elA.y + erA.y)) : 0.f;
    float a2 = lane < degA ? __expf(leaky(elA.z + erA.z)) : 0.f;
    float a3 = lane < degA ? __expf(leaky(elA.w + erA.w)) : 0.f;
    float b0 = lane < degB ? __expf(leaky(elB.x + erB.x)) : 0.f;
    float b1 = lane < degB ? __expf(leaky(elB.y + erB.y)) : 0.f;
    float b2 = lane < degB ? __expf(leaky(elB.z + erB.z)) : 0.f;
    float b3 = lane < degB ? __expf(leaky(elB.w + erB.w)) : 0.f;
    float dA0 = a0, dA1 = a1, dA2 = a2, dA3 = a3;
    float dB0 = b0, dB1 = b1, dB2 = b2, dB3 = b3;
#pragma unroll
    for (int m = 1; m < 64; m <<= 1) {  // 8 independent chains interleave
      dA0 += __shfl_xor(dA0, m);
      dB0 += __shfl_xor(dB0, m);
      dA1 += __shfl_xor(dA1, m);
      dB1 += __shfl_xor(dB1, m);
      dA2 += __shfl_xor(dA2, m);
      dB2 += __shfl_xor(dB2, m);
      dA3 += __shfl_xor(dA3, m);
      dB3 += __shfl_xor(dB3, m);
    }
    unsigned ofA = (unsigned)sA * 512u, ofB = (unsigned)sB * 512u;
    uint4 pa0, pa1, pb0, pb1;
    pa0.x = ofA; pa0.y = __float_as_uint(degA > 0 ? a0 / dA0 : 0.f);
    pa0.z = ofA; pa0.w = __float_as_uint(degA > 0 ? a1 / dA1 : 0.f);
    pa1.x = ofA; pa1.y = __float_as_uint(degA > 0 ? a2 / dA2 : 0.f);
    pa1.z = ofA; pa1.w = __float_as_uint(degA > 0 ? a3 / dA3 : 0.f);
    pb0.x = ofB; pb0.y = __float_as_uint(degB > 0 ? b0 / dB0 : 0.f);
    pb0.z = ofB; pb0.w = __float_as_uint(degB > 0 ? b1 / dB1 : 0.f);
    pb1.x = ofB; pb1.y = __float_as_uint(degB > 0 ? b2 / dB2 : 0.f);
    pb1.z = ofB; pb1.w = __float_as_uint(degB > 0 ? b3 / dB3 : 0.f);
    *(uint4*)&wmeta[wv][0][lane][0] = pa0;
    *(uint4*)&wmeta[wv][0][lane][2] = pa1;
    *(uint4*)&wmeta[wv][1][lane][0] = pb0;
    *(uint4*)&wmeta[wv][1][lane][2] = pb1;
  }

  const int half = lane >> 5, l5 = lane & 31, h = l5 >> 3;
  const char* ftb = (const char*)ft + l5 * 16;  // lane's 16B within a 512B row
  f32x2 accA[4] = {}, accB[4] = {};
  const int degM = max((degA + 7) & ~7, (degB + 7) & ~7);  // pad slots: w=0, safe ofs
  for (int i = 0; i < degM; i += 8) {
    unsigned oA[4], oB[4];
    float wA[4], wB[4];
#pragma unroll
    for (int k = 0; k < 4; ++k) {
      uint2 mAx = wmeta[wv][0][i + k * 2 + half][h];
      uint2 mBx = wmeta[wv][1][i + k * 2 + half][h];
      oA[k] = mAx.x;
      wA[k] = __uint_as_float(mAx.y);
      oB[k] = mBx.x;
      wB[k] = __uint_as_float(mBx.y);
    }
    uint4 uA[4], uB[4];
#pragma unroll
    for (int k = 0; k < 4; ++k) {
      uA[k] = *(const uint4*)(ftb + oA[k]);
      uB[k] = *(const uint4*)(ftb + oB[k]);
    }
#pragma unroll
    for (int k = 0; k < 4; ++k) {
      AGG1_FMA(accA, uA[k], wA[k]);
      AGG1_FMA(accB, uB[k], wB[k]);
    }
  }

#pragma unroll
  for (int j = 0; j < 4; ++j) {
    accA[j][0] += __shfl_xor(accA[j][0], 32);
    accA[j][1] += __shfl_xor(accA[j][1], 32);
    accB[j][0] += __shfl_xor(accB[j][0], 32);
    accB[j][1] += __shfl_xor(accB[j][1], 32);
  }
  // half 0 writes node A, half 1 writes node B: full wave active
  const int node = half ? nodeB : nodeA;
  float v[8];
#pragma unroll
  for (int j = 0; j < 4; ++j) {
    v[2 * j] = half ? accB[j][0] : accA[j][0];
    v[2 * j + 1] = half ? accB[j][1] : accA[j][1];
  }
  float4 b0 = *(const float4*)(bias + l5 * 8);
  float4 b1 = *(const float4*)(bias + l5 * 8 + 4);
  v[0] += b0.x; v[1] += b0.y; v[2] += b0.z; v[3] += b0.w;
  v[4] += b1.x; v[5] += b1.y; v[6] += b1.z; v[7] += b1.w;
#pragma unroll
  for (int k = 0; k < 8; ++k) v[k] = v[k] > 0.f ? v[k] : expm1f(v[k]);
  uint4 o;
  o.x = pack2(v[0], v[1]);
  o.y = pack2(v[2], v[3]);
  o.z = pack2(v[4], v[5]);
  o.w = pack2(v[6], v[7]);
  *(uint4*)(h1 + (size_t)node * 256 + l5 * 8) = o;
}

// ---------- layer-2 aggregate: 2 nodes per wave + residual (CSR) ----------
__launch_bounds__(256)
__global__ void agg2_k(const unsigned short* __restrict__ csr,
                       const unsigned* __restrict__ meta,
                       const float* __restrict__ el, const float* __restrict__ er,
                       const short* __restrict__ ft, float* __restrict__ out) {
  __shared__ uint2 wsl[4][2][64];  // [wave][node][slot] = {byte-ofs, w/denom}
  const int wv = threadIdx.x >> 6;
  const int lane = threadIdx.x & 63;
  const int nodeA = blockIdx.x * 8 + wv * 2;
  const int nodeB = nodeA + 1;
  const unsigned mA = meta[nodeA], mB = meta[nodeB];
  const int degA = (int)(mA >> 25), degB = (int)(mB >> 25);
  const unsigned short* rowA = csr + (mA & 0x1FFFFFFu);
  const unsigned short* rowB = csr + (mB & 0x1FFFFFFu);

  {  // interleaved prologue
    int sA = lane < degA ? (int)rowA[lane] : (degA > 0 ? (int)rowA[0] : 0);
    int sB = lane < degB ? (int)rowB[lane] : (degB > 0 ? (int)rowB[0] : 0);
    float wa = lane < degA ? __expf(leaky(el[sA] + er[nodeA])) : 0.f;
    float wb = lane < degB ? __expf(leaky(el[sB] + er[nodeB])) : 0.f;
    float da = wa, db = wb;
#pragma unroll
    for (int m = 1; m < 64; m <<= 1) {
      da += __shfl_xor(da, m);
      db += __shfl_xor(db, m);
    }
    uint2 ea, eb;
    ea.x = (unsigned)sA * 128u;
    ea.y = __float_as_uint(degA > 0 ? wa / da : 0.f);
    eb.x = (unsigned)sB * 128u;
    eb.y = __float_as_uint(degB > 0 ? wb / db : 0.f);
    wsl[wv][0][lane] = ea;
    wsl[wv][1][lane] = eb;
  }

  const int qtr = lane >> 4, l4 = lane & 15;
  const char* ftb = (const char*)ft + l4 * 8;  // lane's 8B within a 128B row
  f32x2 accA[2] = {}, accB[2] = {};
  const int degM = max((degA + 7) & ~7, (degB + 7) & ~7);
  for (int i = 0; i < degM; i += 8) {
#pragma unroll
    for (int k = 0; k < 2; ++k) {
      int slot = i + k * 4 + qtr;
      uint2 ea = wsl[wv][0][slot];
      uint2 eb = wsl[wv][1][slot];
      uint2 ua = *(const uint2*)(ftb + ea.x);
      uint2 ub = *(const uint2*)(ftb + eb.x);
      float wa = __uint_as_float(ea.y);
      float wb = __uint_as_float(eb.y);
      f32x2 wa2 = {wa, wa}, wb2 = {wb, wb};
      accA[0] += wa2 * (f32x2){bflo(ua.x), bfhi(ua.x)};
      accA[1] += wa2 * (f32x2){bflo(ua.y), bfhi(ua.y)};
      accB[0] += wb2 * (f32x2){bflo(ub.x), bfhi(ub.x)};
      accB[1] += wb2 * (f32x2){bflo(ub.y), bfhi(ub.y)};
    }
  }
#pragma unroll
  for (int j = 0; j < 2; ++j) {
#pragma unroll
    for (int c = 0; c < 2; ++c) {
      accA[j][c] += __shfl_xor(accA[j][c], 16);
      accA[j][c] += __shfl_xor(accA[j][c], 32);
      accB[j][c] += __shfl_xor(accB[j][c], 16);
      accB[j][c] += __shfl_xor(accB[j][c], 32);
    }
  }
  if (lane < 32) {  // lanes 0-15 write A, lanes 16-31 write B
    const int node = lane < 16 ? nodeA : nodeB;
    float4 add;
    add.x = lane < 16 ? accA[0][0] : accB[0][0];
    add.y = lane < 16 ? accA[0][1] : accB[0][1];
    add.z = lane < 16 ? accA[1][0] : accB[1][0];
    add.w = lane < 16 ? accA[1][1] : accB[1][1];
    float4* po = (float4*)(out + (size_t)node * 64 + l4 * 4);
    float4 o = *po;
    o.x += add.x;
    o.y += add.y;
    o.z += add.z;
    o.w += add.w;
    *po = o;
  }
}

// ---------- launch ----------
extern "C" void kernel_launch(void* const* d_in, const int* in_sizes, int n_in,
                              void* d_out, int out_size, void* d_ws, size_t ws_size,
                              hipStream_t stream) {
  const float* feat  = (const float*)d_in[0];
  const int*   src   = (const int*)d_in[1];
  const int*   dst   = (const int*)d_in[2];
  const float* W1    = (const float*)d_in[3];
  const float* al1   = (const float*)d_in[4];
  const float* ar1   = (const float*)d_in[5];
  const float* b1    = (const float*)d_in[6];
  const float* W2    = (const float*)d_in[7];
  const float* al2   = (const float*)d_in[8];
  const float* ar2   = (const float*)d_in[9];
  const float* b2    = (const float*)d_in[10];
  const float* resW2 = (const float*)d_in[11];
  float* out = (float*)d_out;

  char* p = (char*)d_ws;
  short* ft1b = (short*)p; p += (size_t)N_NODES * 256 * 2;
  short* h1b  = (short*)p; p += (size_t)N_NODES * 256 * 2;
  short* ft2b = (short*)p; p += (size_t)N_NODES * 64 * 2;
  short* Wt1  = (short*)p; p += 256 * 256 * 2;
  short* Wt2  = (short*)p; p += 128 * 256 * 2;
  float* el1  = (float*)p; p += (size_t)N_NODES * 4 * 4;
  float* er1  = (float*)p; p += (size_t)N_NODES * 4 * 4;
  float* el2  = (float*)p; p += (size_t)N_NODES * 4;
  float* er2  = (float*)p; p += (size_t)N_NODES * 4;
  unsigned* meta = (unsigned*)p; p += (size_t)N_NODES * 4;
  unsigned short* csr = (unsigned short*)p; p += ((size_t)N_EDGES + 64) * 2;
  unsigned* gcnt = (unsigned*)p; p += 128 * 4;               // NB counters (padded)
  unsigned* bbuf = (unsigned*)p; p += (size_t)NB * BCAP * 4; // ~4 MB bucket entries

  hipMemsetAsync(gcnt, 0, 128 * sizeof(unsigned), stream);

  dim3 blk(256);

  // prep: binning pass1 strip (dispatched first) + weight packs
  prep_k<<<BIN_BLKS + CONV_BLKS, blk, 0, stream>>>(W1, W2, resW2, Wt1, Wt2,
                                                   src, dst, gcnt, bbuf);

  // layer 1 GEMM from FP32 feat (+fused el1/er1); y==0 strip = CSR pass2
  mfma_gemm_k<0, true><<<dim3(391, 3), blk, 0, stream>>>(
      nullptr, feat, Wt1, nullptr, al1, ar1, el1, er1, ft1b, nullptr,
      gcnt, bbuf, meta, csr, N_NODES, 256, 256);
  // two half dispatches (visibility: lets other kernels surface in top-5)
  agg1_k<<<3125, blk, 0, stream>>>(csr, meta, el1, er1, ft1b, b1, h1b, 0);
  agg1_k<<<3125, blk, 0, stream>>>(csr, meta, el1, er1, ft1b, b1, h1b, 25000);

  // layer 2: [ft2 | res+b2] = h1 @ [W2 | resW2] + fused el2/er2
  mfma_gemm_k<1, false><<<dim3(391, 1), blk, 0, stream>>>(
      h1b, nullptr, Wt2, b2, al2, ar2, el2, er2, ft2b, out,
      nullptr, nullptr, nullptr, nullptr, N_NODES, 256, 128);
  agg2_k<<<6250, blk, 0, stream>>>(csr, meta, el2, er2, ft2b, out);
}

// Round 12
// 262.302 us; speedup vs baseline: 1.0113x; 1.0113x over previous
//
#include <hip/hip_runtime.h>
#include <math.h>

#define N_NODES 50000
#define N_EDGES 800000
#define ELL_W 64   // max in-degree ~45 (Poisson mean 16); 64 is safe

// two-pass binning ELL builder:
// pass1 (prep strip): 250 blocks x 3200 edges -> 392 buckets of 128 nodes (dst>>7)
// pass2 (gemm1 strip): 392 blocks, direct LDS-ELL build + dense coalesced copy-out
#define NB 392
#define BCAP 2816    // mean 2048, std ~45 -> 17 sigma headroom
#define BIN_BLKS 250
#define CONV_BLKS 256

typedef __attribute__((ext_vector_type(8))) short bf16x8;
typedef __attribute__((ext_vector_type(4))) float f32x4;
typedef __attribute__((ext_vector_type(2))) float f32x2;

__device__ __forceinline__ float leaky(float x) { return x >= 0.f ? x : 0.2f * x; }
__device__ __forceinline__ unsigned short f2bf(float f) {
  unsigned u = __float_as_uint(f);
  return (unsigned short)((u + 0x7fffu + ((u >> 16) & 1u)) >> 16);
}
__device__ __forceinline__ float bflo(unsigned u) { return __uint_as_float(u << 16); }
__device__ __forceinline__ float bfhi(unsigned u) { return __uint_as_float(u & 0xffff0000u); }
__device__ __forceinline__ unsigned pack2(float a, float b) {
  return (unsigned)f2bf(a) | ((unsigned)f2bf(b) << 16);
}
__device__ __forceinline__ unsigned pack2u(unsigned a, unsigned b) {
  return pack2(__uint_as_float(a), __uint_as_float(b));
}

// ---------- prep: binning pass1 strip (FIRST) + weight packs ----------
__launch_bounds__(256)
__global__ void prep_k(const float* __restrict__ W1, const float* __restrict__ W2,
                       const float* __restrict__ resW2, short* __restrict__ Wt1,
                       short* __restrict__ Wt2, const int* __restrict__ src,
                       const int* __restrict__ dst, unsigned* __restrict__ gcnt,
                       unsigned* __restrict__ bbuf) {
  __shared__ int hist[NB];
  __shared__ int basev[NB];
  if (blockIdx.x < BIN_BLKS) {
    const int e0 = blockIdx.x * (N_EDGES / BIN_BLKS);  // 3200 edges per block
    for (int i = threadIdx.x; i < NB; i += 256) hist[i] = 0;
    __syncthreads();
    for (int i = threadIdx.x; i < N_EDGES / BIN_BLKS; i += 256)
      atomicAdd(&hist[dst[e0 + i] >> 7], 1);
    __syncthreads();
    for (int b = threadIdx.x; b < NB; b += 256)
      basev[b] = (int)atomicAdd(&gcnt[b], (unsigned)hist[b]);  // 392 atomics/block
    __syncthreads();
    for (int i = threadIdx.x; i < NB; i += 256) hist[i] = 0;
    __syncthreads();
    for (int i = threadIdx.x; i < N_EDGES / BIN_BLKS; i += 256) {
      int d = dst[e0 + i], s = src[e0 + i];  // L2-hot re-read
      int b = d >> 7;
      int ofs = atomicAdd(&hist[b], 1);
      int pos = basev[b] + ofs;
      if (pos < BCAP)
        bbuf[(size_t)b * BCAP + pos] = (unsigned)s | ((unsigned)(d & 127) << 16);
    }
    return;
  }
  const int gtid = (blockIdx.x - BIN_BLKS) * 256 + threadIdx.x;
  const int gsz = CONV_BLKS * 256;
  for (int idx = gtid; idx < 256 * 256; idx += gsz) {
    int n = idx >> 8, k = idx & 255;
    Wt1[idx] = (short)f2bf(W1[(size_t)k * 256 + n]);
  }
  for (int idx = gtid; idx < 128 * 256; idx += gsz) {
    int n = idx >> 8, k = idx & 255;
    float v = (n < 64) ? W2[(size_t)k * 64 + n] : resW2[(size_t)k * 64 + (n - 64)];
    Wt2[idx] = (short)f2bf(v);
  }
}

// ---------- bf16 MFMA GEMM with fused el/er row-dot + LDS-coalesced C store ----------
// MODE 0: A is FP32 (feat), converted to bf16 in-register during staging.
//         SCAT: blockIdx.y==0 (dispatched FIRST) runs pass2 (x<NB): build the
//         bucket's 128x64 ELL tile in LDS (1 atomic + 1 LDS write per entry),
//         dense coalesced copy-out. Bucket-strided: no cross-bucket prefix.
//         GEMM tiles at y in {1,2} with bn0=(y-1)*128.
// MODE 1: A is bf16 (h1b). N=128; cols<64 -> bf16 Cb + el/er; cols>=64 -> fp32 Cf.
template <int MODE, bool SCAT>
__launch_bounds__(256)
__global__ void mfma_gemm_k(const short* __restrict__ A, const float* __restrict__ Af,
                            const short* __restrict__ Bt,
                            const float* __restrict__ bias, const float* __restrict__ al,
                            const float* __restrict__ ar, float* __restrict__ elp,
                            float* __restrict__ erp, short* __restrict__ Cb,
                            float* __restrict__ Cf, const unsigned* __restrict__ gcnt,
                            const unsigned* __restrict__ bbuf, int* __restrict__ cnt,
                            unsigned short* __restrict__ ell, int M, int K, int N) {
  constexpr int EPI_COLS = (MODE == 0) ? 136 : 72;  // padded bf16 row stride
  union SharedU {
    struct { short As[4][128][8]; short Bs[4][128][8]; } ab;
    short epi[128 * EPI_COLS];
    struct { int h[128]; unsigned short lell[128 * ELL_W]; } p2;  // 16.9 KB
  };
  __shared__ SharedU sh;

  if (SCAT && blockIdx.y == 0) {
    // pass2: direct LDS-ELL build per bucket; all global stores coalesced
    if (blockIdx.x >= NB) return;
    const int b = blockIdx.x;
    const int tid = threadIdx.x;
    int* h = sh.p2.h;
    unsigned short* lell = sh.p2.lell;
    for (int i = tid; i < 128; i += 256) h[i] = 0;
    __syncthreads();
    const int nb = min((int)gcnt[b], BCAP);
    const unsigned* bp = bbuf + (size_t)b * BCAP;
    for (int i = tid; i < nb; i += 256) {
      unsigned e = bp[i];
      int dl = (int)(e >> 16);
      int sl = atomicAdd(&h[dl], 1);
      if (sl < ELL_W) lell[dl * ELL_W + sl] = (unsigned short)(e & 0xFFFFu);
    }
    __syncthreads();
    // dense 16KB copy-out (uint4) + cnt
    {
      const uint4* ls = (const uint4*)lell;
      uint4* gd = (uint4*)(ell + (size_t)b * 128 * ELL_W);
#pragma unroll
      for (int k = 0; k < 4; ++k) gd[k * 256 + tid] = ls[k * 256 + tid];
    }
    const int base = b << 7;
    for (int i = tid; i < 128; i += 256) {
      int node = base + i;
      if (node < N_NODES) cnt[node] = min(h[i], ELL_W);
    }
    return;
  }
  const int tid = threadIdx.x;
  const int bm0 = blockIdx.x * 128;
  const int bn0 = (SCAT ? ((int)blockIdx.y - 1) : (int)blockIdx.y) * 128;
  const int wave = tid >> 6, lane = tid & 63;
  const int wm = (wave & 1) * 64, wn = (wave >> 1) * 64;
  const int q = lane >> 4, r16 = lane & 15;
  const int srow = tid >> 1, sk = (tid & 1) * 16, sq = (tid & 1) * 2;
  f32x4 acc[4][4] = {};

  for (int k0 = 0; k0 < K; k0 += 32) {
    if (MODE == 0) {
      // FP32 A: load 16 floats (4x uint4), pack to bf16 in-register
      uint4 w0 = {0, 0, 0, 0}, w1 = {0, 0, 0, 0}, w2 = {0, 0, 0, 0}, w3 = {0, 0, 0, 0};
      if (bm0 + srow < M) {
        const uint4* p = (const uint4*)(Af + (size_t)(bm0 + srow) * K + k0 + sk);
        w0 = p[0];
        w1 = p[1];
        w2 = p[2];
        w3 = p[3];
      }
      uint4 v0, v1;
      v0.x = pack2u(w0.x, w0.y);
      v0.y = pack2u(w0.z, w0.w);
      v0.z = pack2u(w1.x, w1.y);
      v0.w = pack2u(w1.z, w1.w);
      v1.x = pack2u(w2.x, w2.y);
      v1.y = pack2u(w2.z, w2.w);
      v1.z = pack2u(w3.x, w3.y);
      v1.w = pack2u(w3.z, w3.w);
      *(uint4*)&sh.ab.As[sq][srow][0] = v0;
      *(uint4*)&sh.ab.As[sq + 1][srow][0] = v1;
    } else {
      uint4 v0 = {0, 0, 0, 0}, v1 = {0, 0, 0, 0};
      if (bm0 + srow < M) {
        const uint4* p = (const uint4*)(A + (size_t)(bm0 + srow) * K + k0 + sk);
        v0 = p[0];
        v1 = p[1];
      }
      *(uint4*)&sh.ab.As[sq][srow][0] = v0;
      *(uint4*)&sh.ab.As[sq + 1][srow][0] = v1;
    }
    {
      const uint4* p = (const uint4*)(Bt + (size_t)(bn0 + srow) * K + k0 + sk);
      *(uint4*)&sh.ab.Bs[sq][srow][0] = p[0];
      *(uint4*)&sh.ab.Bs[sq + 1][srow][0] = p[1];
    }
    __syncthreads();
    bf16x8 af[4], bfr[4];
#pragma unroll
    for (int i = 0; i < 4; ++i) af[i] = *(const bf16x8*)&sh.ab.As[q][wm + i * 16 + r16][0];
#pragma unroll
    for (int j = 0; j < 4; ++j) bfr[j] = *(const bf16x8*)&sh.ab.Bs[q][wn + j * 16 + r16][0];
#pragma unroll
    for (int i = 0; i < 4; ++i)
#pragma unroll
      for (int j = 0; j < 4; ++j)
        acc[i][j] = __builtin_amdgcn_mfma_f32_16x16x32_bf16(af[i], bfr[j], acc[i][j], 0, 0, 0);
    __syncthreads();
  }

  // fused el/er row-dot: this wave's 64 cols are exactly one head (regs only)
  if (MODE == 0 || wn == 0) {
    const int head = (bn0 + wn) >> 6;
    float alv[4], arv[4];
#pragma unroll
    for (int j = 0; j < 4; ++j) {
      alv[j] = al[((MODE == 0) ? head * 64 : 0) + j * 16 + r16];
      arv[j] = ar[((MODE == 0) ? head * 64 : 0) + j * 16 + r16];
    }
#pragma unroll
    for (int i = 0; i < 4; ++i) {
#pragma unroll
      for (int reg = 0; reg < 4; ++reg) {
        float dl = acc[i][0][reg] * alv[0] + acc[i][1][reg] * alv[1] +
                   acc[i][2][reg] * alv[2] + acc[i][3][reg] * alv[3];
        float dr = acc[i][0][reg] * arv[0] + acc[i][1][reg] * arv[1] +
                   acc[i][2][reg] * arv[2] + acc[i][3][reg] * arv[3];
#pragma unroll
        for (int mm = 1; mm < 16; mm <<= 1) {
          dl += __shfl_xor(dl, mm);
          dr += __shfl_xor(dr, mm);
        }
        int row_g = bm0 + wm + i * 16 + q * 4 + reg;
        if (r16 == 0 && row_g < M) {
          if (MODE == 0) {
            elp[(size_t)row_g * 4 + head] = dl;
            erp[(size_t)row_g * 4 + head] = dr;
          } else {
            elp[row_g] = dl;
            erp[row_g] = dr;
          }
        }
      }
    }
  }

  // ---- C store via LDS transpose -> coalesced uint4 ----
  if (MODE == 0) {
#pragma unroll
    for (int i = 0; i < 4; ++i)
#pragma unroll
      for (int reg = 0; reg < 4; ++reg) {
        int row = wm + i * 16 + q * 4 + reg;
#pragma unroll
        for (int j = 0; j < 4; ++j)
          sh.epi[row * EPI_COLS + wn + j * 16 + r16] = (short)f2bf(acc[i][j][reg]);
      }
    __syncthreads();
#pragma unroll
    for (int k = 0; k < 8; ++k) {
      int c = k * 256 + tid;          // 2048 chunks of 16B
      int row = c >> 4, cc = c & 15;  // 128 rows x 16 chunks
      int row_g = bm0 + row;
      if (row_g < M) {
        uint4 v = *(const uint4*)&sh.epi[row * EPI_COLS + cc * 8];
        *(uint4*)(Cb + (size_t)row_g * N + bn0 + cc * 8) = v;
      }
    }
  } else {
    if (wn == 0) {
#pragma unroll
      for (int i = 0; i < 4; ++i)
#pragma unroll
        for (int reg = 0; reg < 4; ++reg) {
          int row = wm + i * 16 + q * 4 + reg;
#pragma unroll
          for (int j = 0; j < 4; ++j)
            sh.epi[row * EPI_COLS + j * 16 + r16] = (short)f2bf(acc[i][j][reg]);
        }
    } else {
#pragma unroll
      for (int i = 0; i < 4; ++i)
#pragma unroll
        for (int reg = 0; reg < 4; ++reg) {
          int row_g = bm0 + wm + i * 16 + q * 4 + reg;
          if (row_g >= M) continue;
#pragma unroll
          for (int j = 0; j < 4; ++j) {
            int col = j * 16 + r16;
            Cf[(size_t)row_g * 64 + col] = acc[i][j][reg] + bias[col];
          }
        }
    }
    __syncthreads();
#pragma unroll
    for (int k = 0; k < 4; ++k) {
      int c = k * 256 + tid;         // 1024 chunks of 16B
      int row = c >> 3, cc = c & 7;  // 128 rows x 8 chunks
      int row_g = bm0 + row;
      if (row_g < M) {
        uint4 v = *(const uint4*)&sh.epi[row * EPI_COLS + cc * 8];
        *(uint4*)(Cb + (size_t)row_g * 64 + cc * 8) = v;
      }
    }
  }
}

// ---------- layer-1 aggregate: 2 independent nodes per wave (cross-node ILP) ----------
#define AGG1_FMA(ACC, U, W)                     \
  {                                             \
    f32x2 w2_ = {(W), (W)};                     \
    ACC[0] += w2_ * (f32x2){bflo((U).x), bfhi((U).x)}; \
    ACC[1] += w2_ * (f32x2){bflo((U).y), bfhi((U).y)}; \
    ACC[2] += w2_ * (f32x2){bflo((U).z), bfhi((U).z)}; \
    ACC[3] += w2_ * (f32x2){bflo((U).w), bfhi((U).w)}; \
  }

__launch_bounds__(256)
__global__ void agg1_k(const unsigned short* __restrict__ ell, const int* __restrict__ cnt,
                       const float* __restrict__ el, const float* __restrict__ er,
                       const short* __restrict__ ft, const float* __restrict__ bias,
                       short* __restrict__ h1) {
  __shared__ uint2 wmeta[4][2][64][4];  // [wave][node][slot][head] = {byte-ofs, w/denom}
  const int wv = threadIdx.x >> 6;
  const int lane = threadIdx.x & 63;
  const int nodeA = blockIdx.x * 8 + wv * 2;  // grid 6250*8 = 50000 exact
  const int nodeB = nodeA + 1;
  const int degA = cnt[nodeA];
  const int degB = cnt[nodeB];
  const unsigned short* rowA = ell + (size_t)nodeA * ELL_W;
  const unsigned short* rowB = ell + (size_t)nodeB * ELL_W;

  {  // interleaved prologue (same wave produces & consumes: no barrier)
    int sA = lane < degA ? (int)rowA[lane] : (degA > 0 ? (int)rowA[0] : 0);
    int sB = lane < degB ? (int)rowB[lane] : (degB > 0 ? (int)rowB[0] : 0);
    float4 elA = *(const float4*)(el + (size_t)sA * 4);
    float4 elB = *(const float4*)(el + (size_t)sB * 4);
    float4 erA = *(const float4*)(er + (size_t)nodeA * 4);
    float4 erB = *(const float4*)(er + (size_t)nodeB * 4);
    float a0 = lane < degA ? __expf(leaky(elA.x + erA.x)) : 0.f;
    float a1 = lane < degA ? __expf(leaky(elA.y + erA.y)) : 0.f;
    float a2 = lane < degA ? __expf(leaky(elA.z + erA.z)) : 0.f;
    float a3 = lane < degA ? __expf(leaky(elA.w + erA.w)) : 0.f;
    float b0 = lane < degB ? __expf(leaky(elB.x + erB.x)) : 0.f;
    float b1 = lane < degB ? __expf(leaky(elB.y + erB.y)) : 0.f;
    float b2 = lane < degB ? __expf(leaky(elB.z + erB.z)) : 0.f;
    float b3 = lane < degB ? __expf(leaky(elB.w + erB.w)) : 0.f;
    float dA0 = a0, dA1 = a1, dA2 = a2, dA3 = a3;
    float dB0 = b0, dB1 = b1, dB2 = b2, dB3 = b3;
#pragma unroll
    for (int m = 1; m < 64; m <<= 1) {  // 8 independent chains interleave
      dA0 += __shfl_xor(dA0, m);
      dB0 += __shfl_xor(dB0, m);
      dA1 += __shfl_xor(dA1, m);
      dB1 += __shfl_xor(dB1, m);
      dA2 += __shfl_xor(dA2, m);
      dB2 += __shfl_xor(dB2, m);
      dA3 += __shfl_xor(dA3, m);
      dB3 += __shfl_xor(dB3, m);
    }
    unsigned ofA = (unsigned)sA * 512u, ofB = (unsigned)sB * 512u;
    uint4 pa0, pa1, pb0, pb1;
    pa0.x = ofA; pa0.y = __float_as_uint(degA > 0 ? a0 / dA0 : 0.f);
    pa0.z = ofA; pa0.w = __float_as_uint(degA > 0 ? a1 / dA1 : 0.f);
    pa1.x = ofA; pa1.y = __float_as_uint(degA > 0 ? a2 / dA2 : 0.f);
    pa1.z = ofA; pa1.w = __float_as_uint(degA > 0 ? a3 / dA3 : 0.f);
    pb0.x = ofB; pb0.y = __float_as_uint(degB > 0 ? b0 / dB0 : 0.f);
    pb0.z = ofB; pb0.w = __float_as_uint(degB > 0 ? b1 / dB1 : 0.f);
    pb1.x = ofB; pb1.y = __float_as_uint(degB > 0 ? b2 / dB2 : 0.f);
    pb1.z = ofB; pb1.w = __float_as_uint(degB > 0 ? b3 / dB3 : 0.f);
    *(uint4*)&wmeta[wv][0][lane][0] = pa0;
    *(uint4*)&wmeta[wv][0][lane][2] = pa1;
    *(uint4*)&wmeta[wv][1][lane][0] = pb0;
    *(uint4*)&wmeta[wv][1][lane][2] = pb1;
  }

  const int half = lane >> 5, l5 = lane & 31, h = l5 >> 3;
  const char* ftb = (const char*)ft + l5 * 16;  // lane's 16B within a 512B row
  f32x2 accA[4] = {}, accB[4] = {};
  const int degM = max((degA + 7) & ~7, (degB + 7) & ~7);  // pad slots: w=0, safe ofs
  for (int i = 0; i < degM; i += 8) {
    unsigned oA[4], oB[4];
    float wA[4], wB[4];
#pragma unroll
    for (int k = 0; k < 4; ++k) {
      uint2 mA = wmeta[wv][0][i + k * 2 + half][h];
      uint2 mB = wmeta[wv][1][i + k * 2 + half][h];
      oA[k] = mA.x;
      wA[k] = __uint_as_float(mA.y);
      oB[k] = mB.x;
      wB[k] = __uint_as_float(mB.y);
    }
    uint4 uA[4], uB[4];
#pragma unroll
    for (int k = 0; k < 4; ++k) {
      uA[k] = *(const uint4*)(ftb + oA[k]);
      uB[k] = *(const uint4*)(ftb + oB[k]);
    }
#pragma unroll
    for (int k = 0; k < 4; ++k) {
      AGG1_FMA(accA, uA[k], wA[k]);
      AGG1_FMA(accB, uB[k], wB[k]);
    }
  }

#pragma unroll
  for (int j = 0; j < 4; ++j) {
    accA[j][0] += __shfl_xor(accA[j][0], 32);
    accA[j][1] += __shfl_xor(accA[j][1], 32);
    accB[j][0] += __shfl_xor(accB[j][0], 32);
    accB[j][1] += __shfl_xor(accB[j][1], 32);
  }
  // half 0 writes node A, half 1 writes node B: full wave active
  const int node = half ? nodeB : nodeA;
  float v[8];
#pragma unroll
  for (int j = 0; j < 4; ++j) {
    v[2 * j] = half ? accB[j][0] : accA[j][0];
    v[2 * j + 1] = half ? accB[j][1] : accA[j][1];
  }
  float4 b0 = *(const float4*)(bias + l5 * 8);
  float4 b1 = *(const float4*)(bias + l5 * 8 + 4);
  v[0] += b0.x; v[1] += b0.y; v[2] += b0.z; v[3] += b0.w;
  v[4] += b1.x; v[5] += b1.y; v[6] += b1.z; v[7] += b1.w;
#pragma unroll
  for (int k = 0; k < 8; ++k) v[k] = v[k] > 0.f ? v[k] : expm1f(v[k]);
  uint4 o;
  o.x = pack2(v[0], v[1]);
  o.y = pack2(v[2], v[3]);
  o.z = pack2(v[4], v[5]);
  o.w = pack2(v[6], v[7]);
  *(uint4*)(h1 + (size_t)node * 256 + l5 * 8) = o;
}

// ---------- layer-2 aggregate: 2 nodes per wave + residual ----------
__launch_bounds__(256)
__global__ void agg2_k(const unsigned short* __restrict__ ell, const int* __restrict__ cnt,
                       const float* __restrict__ el, const float* __restrict__ er,
                       const short* __restrict__ ft, float* __restrict__ out) {
  __shared__ uint2 wsl[4][2][64];  // [wave][node][slot] = {byte-ofs, w/denom}
  const int wv = threadIdx.x >> 6;
  const int lane = threadIdx.x & 63;
  const int nodeA = blockIdx.x * 8 + wv * 2;
  const int nodeB = nodeA + 1;
  const int degA = cnt[nodeA];
  const int degB = cnt[nodeB];
  const unsigned short* rowA = ell + (size_t)nodeA * ELL_W;
  const unsigned short* rowB = ell + (size_t)nodeB * ELL_W;

  {  // interleaved prologue
    int sA = lane < degA ? (int)rowA[lane] : (degA > 0 ? (int)rowA[0] : 0);
    int sB = lane < degB ? (int)rowB[lane] : (degB > 0 ? (int)rowB[0] : 0);
    float wa = lane < degA ? __expf(leaky(el[sA] + er[nodeA])) : 0.f;
    float wb = lane < degB ? __expf(leaky(el[sB] + er[nodeB])) : 0.f;
    float da = wa, db = wb;
#pragma unroll
    for (int m = 1; m < 64; m <<= 1) {
      da += __shfl_xor(da, m);
      db += __shfl_xor(db, m);
    }
    uint2 ea, eb;
    ea.x = (unsigned)sA * 128u;
    ea.y = __float_as_uint(degA > 0 ? wa / da : 0.f);
    eb.x = (unsigned)sB * 128u;
    eb.y = __float_as_uint(degB > 0 ? wb / db : 0.f);
    wsl[wv][0][lane] = ea;
    wsl[wv][1][lane] = eb;
  }

  const int qtr = lane >> 4, l4 = lane & 15;
  const char* ftb = (const char*)ft + l4 * 8;  // lane's 8B within a 128B row
  f32x2 accA[2] = {}, accB[2] = {};
  const int degM = max((degA + 7) & ~7, (degB + 7) & ~7);
  for (int i = 0; i < degM; i += 8) {
#pragma unroll
    for (int k = 0; k < 2; ++k) {
      int slot = i + k * 4 + qtr;
      uint2 ea = wsl[wv][0][slot];
      uint2 eb = wsl[wv][1][slot];
      uint2 ua = *(const uint2*)(ftb + ea.x);
      uint2 ub = *(const uint2*)(ftb + eb.x);
      float wa = __uint_as_float(ea.y);
      float wb = __uint_as_float(eb.y);
      f32x2 wa2 = {wa, wa}, wb2 = {wb, wb};
      accA[0] += wa2 * (f32x2){bflo(ua.x), bfhi(ua.x)};
      accA[1] += wa2 * (f32x2){bflo(ua.y), bfhi(ua.y)};
      accB[0] += wb2 * (f32x2){bflo(ub.x), bfhi(ub.x)};
      accB[1] += wb2 * (f32x2){bflo(ub.y), bfhi(ub.y)};
    }
  }
#pragma unroll
  for (int j = 0; j < 2; ++j) {
#pragma unroll
    for (int c = 0; c < 2; ++c) {
      accA[j][c] += __shfl_xor(accA[j][c], 16);
      accA[j][c] += __shfl_xor(accA[j][c], 32);
      accB[j][c] += __shfl_xor(accB[j][c], 16);
      accB[j][c] += __shfl_xor(accB[j][c], 32);
    }
  }
  if (lane < 32) {  // lanes 0-15 write A, lanes 16-31 write B
    const int node = lane < 16 ? nodeA : nodeB;
    float4 add;
    add.x = lane < 16 ? accA[0][0] : accB[0][0];
    add.y = lane < 16 ? accA[0][1] : accB[0][1];
    add.z = lane < 16 ? accA[1][0] : accB[1][0];
    add.w = lane < 16 ? accA[1][1] : accB[1][1];
    float4* po = (float4*)(out + (size_t)node * 64 + l4 * 4);
    float4 o = *po;
    o.x += add.x;
    o.y += add.y;
    o.z += add.z;
    o.w += add.w;
    *po = o;
  }
}

// ---------- launch ----------
extern "C" void kernel_launch(void* const* d_in, const int* in_sizes, int n_in,
                              void* d_out, int out_size, void* d_ws, size_t ws_size,
                              hipStream_t stream) {
  const float* feat  = (const float*)d_in[0];
  const int*   src   = (const int*)d_in[1];
  const int*   dst   = (const int*)d_in[2];
  const float* W1    = (const float*)d_in[3];
  const float* al1   = (const float*)d_in[4];
  const float* ar1   = (const float*)d_in[5];
  const float* b1    = (const float*)d_in[6];
  const float* W2    = (const float*)d_in[7];
  const float* al2   = (const float*)d_in[8];
  const float* ar2   = (const float*)d_in[9];
  const float* b2    = (const float*)d_in[10];
  const float* resW2 = (const float*)d_in[11];
  float* out = (float*)d_out;

  char* p = (char*)d_ws;
  short* ft1b = (short*)p; p += (size_t)N_NODES * 256 * 2;
  short* h1b  = (short*)p; p += (size_t)N_NODES * 256 * 2;
  short* ft2b = (short*)p; p += (size_t)N_NODES * 64 * 2;
  short* Wt1  = (short*)p; p += 256 * 256 * 2;
  short* Wt2  = (short*)p; p += 128 * 256 * 2;
  float* el1  = (float*)p; p += (size_t)N_NODES * 4 * 4;
  float* er1  = (float*)p; p += (size_t)N_NODES * 4 * 4;
  float* el2  = (float*)p; p += (size_t)N_NODES * 4;
  float* er2  = (float*)p; p += (size_t)N_NODES * 4;
  int* cnt    = (int*)p;   p += (size_t)N_NODES * 4;
  unsigned short* ell = (unsigned short*)p; p += (size_t)NB * 128 * ELL_W * 2;  // 6.4MB
  unsigned* gcnt = (unsigned*)p; p += 512 * 4;               // NB counters (padded)
  unsigned* bbuf = (unsigned*)p; p += (size_t)NB * BCAP * 4; // ~4.4MB bucket entries

  hipMemsetAsync(gcnt, 0, 512 * sizeof(unsigned), stream);

  dim3 blk(256);

  // prep: binning pass1 strip (dispatched first) + weight packs
  prep_k<<<BIN_BLKS + CONV_BLKS, blk, 0, stream>>>(W1, W2, resW2, Wt1, Wt2,
                                                   src, dst, gcnt, bbuf);

  // layer 1 GEMM from FP32 feat (+fused el1/er1); y==0 strip = ELL pass2
  // grid.x=392 covers all pass2 buckets; GEMM tile x=391 is fully masked (safe)
  mfma_gemm_k<0, true><<<dim3(392, 3), blk, 0, stream>>>(
      nullptr, feat, Wt1, nullptr, al1, ar1, el1, er1, ft1b, nullptr,
      gcnt, bbuf, cnt, ell, N_NODES, 256, 256);
  agg1_k<<<6250, blk, 0, stream>>>(ell, cnt, el1, er1, ft1b, b1, h1b);

  // layer 2: [ft2 | res+b2] = h1 @ [W2 | resW2] + fused el2/er2
  mfma_gemm_k<1, false><<<dim3(391, 1), blk, 0, stream>>>(
      h1b, nullptr, Wt2, b2, al2, ar2, el2, er2, ft2b, out,
      nullptr, nullptr, nullptr, nullptr, N_NODES, 256, 128);
  agg2_k<<<6250, blk, 0, stream>>>(ell, cnt, el2, er2, ft2b, out);
}